// Round 4
// baseline (142.405 us; speedup 1.0000x reference)
//
#include <hip/hip_runtime.h>
#include <math.h>

typedef __attribute__((ext_vector_type(8))) __bf16 bf16x8;
typedef __attribute__((ext_vector_type(4))) __bf16 bf16x4v;
typedef __attribute__((ext_vector_type(16))) float f32x16;

#define N_TOK  4096
#define C_DIM  1024
#define N_EXP  8
#define CAP    4096

// workspace layout (bytes). ws_size ~= 256 MiB (poison-fill WRITE_SIZE evidence).
// NOTE round-3 postmortem: '<<' binds looser than '+' — keep offsets parenthesized.
#define WS_CNT    0                                   // 32 B
#define WS_PERM   32768                               // 128 KB: per-expert slot lists
#define WS_XB     ((size_t)1 << 20)                   // 8 MB: x in bf16
#define WS_WT     (WS_XB + ((size_t)8 << 20))         // 16 MB: W^T bf16

// async global->LDS, 16B per lane. LDS dest is wave-uniform base + lane*16.
#define GLD16(g, l)                                                        \
  __builtin_amdgcn_global_load_lds(                                        \
      (const __attribute__((address_space(1))) void*)(g),                  \
      (__attribute__((address_space(3))) void*)(l), 16, 0, 0)

// ---------------------------------------------------------------------------
// prep: fused router (blocks 0..255) + W transpose/bf16 (blocks 256..8447).
// Router blocks also build the per-expert slot lists (LDS-aggregated counts
// -> 8 spread global atomics per block; cnt pre-zeroed by a 32 B memset).
// ---------------------------------------------------------------------------
__global__ __launch_bounds__(256)
void prep_kernel(const float* __restrict__ x, const float* __restrict__ wg,
                 const float* __restrict__ bias, const float* __restrict__ W,
                 __bf16* __restrict__ xb, float* __restrict__ probs,
                 __bf16* __restrict__ Wt, int* __restrict__ cnt,
                 int* __restrict__ perm) {
  __shared__ __align__(16) char smem[32768];
  __shared__ int lcnt[N_EXP], base[N_EXP];
  const int tid = threadIdx.x;

  if (blockIdx.x < 256) {
    // ---------------- router ----------------
    float (*wgT)[C_DIM] = (float (*)[C_DIM])smem;   // [N_EXP][C_DIM], 32 KB
    if (tid < N_EXP) lcnt[tid] = 0;

#pragma unroll
    for (int i = 0; i < 8; ++i) {
      const float4 v = ((const float4*)wg)[i * 256 + tid];
      const int f = (i * 256 + tid) * 4;
      const int c = f >> 3;
      const int e = f & 7;
      wgT[e][c] = v.x; wgT[e + 1][c] = v.y; wgT[e + 2][c] = v.z; wgT[e + 3][c] = v.w;
    }
    __syncthreads();

    const int lane = tid & 63;
    const int wv   = tid >> 6;
    int re0[4], re1[4], rs0[4], rs1[4];   // lane0-valid per s

#pragma unroll
    for (int s = 0; s < 4; ++s) {
      const int t = blockIdx.x * 16 + wv * 4 + s;
      const float4* xrow = (const float4*)(x + (size_t)t * C_DIM);
      float acc[N_EXP];
#pragma unroll
      for (int e = 0; e < N_EXP; ++e) acc[e] = 0.f;

#pragma unroll
      for (int j = 0; j < 4; ++j) {
        const int c4 = j * 64 + lane;
        const float4 v = xrow[c4];
        bf16x4v bv = { (__bf16)v.x, (__bf16)v.y, (__bf16)v.z, (__bf16)v.w };
        *(bf16x4v*)(xb + (size_t)t * C_DIM + c4 * 4) = bv;
#pragma unroll
        for (int e = 0; e < N_EXP; ++e) {
          const float4 w = *(const float4*)&wgT[e][c4 * 4];
          acc[e] += v.x * w.x + v.y * w.y + v.z * w.z + v.w * w.w;
        }
      }

#pragma unroll
      for (int off = 32; off >= 1; off >>= 1) {
#pragma unroll
        for (int e = 0; e < N_EXP; ++e) acc[e] += __shfl_xor(acc[e], off, 64);
      }

      if (lane == 0) {
        float l[N_EXP];
#pragma unroll
        for (int e = 0; e < N_EXP; ++e) l[e] = acc[e] + bias[e];
        int e0 = 0;
#pragma unroll
        for (int e = 1; e < N_EXP; ++e) if (l[e] > l[e0]) e0 = e;
        int e1 = (e0 == 0) ? 1 : 0;
#pragma unroll
        for (int e = 0; e < N_EXP; ++e) if (e != e0 && l[e] > l[e1]) e1 = e;
        const float p0 = 1.f / (1.f + expf(l[e1] - l[e0]));
        probs[t * 2]     = p0;
        probs[t * 2 + 1] = 1.f - p0;
        re0[s] = e0; re1[s] = e1;
        rs0[s] = atomicAdd(&lcnt[e0], 1);
        rs1[s] = atomicAdd(&lcnt[e1], 1);
      }
    }
    __syncthreads();
    if (tid < N_EXP) base[tid] = atomicAdd(&cnt[tid], lcnt[tid]);
    __syncthreads();
    if (lane == 0) {
#pragma unroll
      for (int s = 0; s < 4; ++s) {
        const int t = blockIdx.x * 16 + wv * 4 + s;
        perm[re0[s] * CAP + base[re0[s]] + rs0[s]] = t * 2;
        perm[re1[s] * CAP + base[re1[s]] + rs1[s]] = t * 2 + 1;
      }
    }
  } else {
    // ---------------- W transpose + bf16 convert ----------------
    __bf16 (*tile)[33] = (__bf16 (*)[33])smem;      // [32][33]
    const int b  = blockIdx.x - 256;
    const int e  = b >> 10;
    const int r  = b & 1023;
    const int i0 = (r >> 5) * 32;
    const int o0 = (r & 31) * 32;
    const float* We  = W  + (size_t)e * C_DIM * C_DIM;
    __bf16*      Wte = Wt + (size_t)e * C_DIM * C_DIM;
    const int tx = tid & 31, ty = tid >> 5;
#pragma unroll
    for (int j = 0; j < 32; j += 8)
      tile[ty + j][tx] = (__bf16)We[(size_t)(i0 + ty + j) * C_DIM + o0 + tx];
    __syncthreads();
#pragma unroll
    for (int j = 0; j < 32; j += 8)
      Wte[(size_t)(o0 + ty + j) * C_DIM + i0 + tx] = tile[tx][ty + j];
  }
}

// ---------------------------------------------------------------------------
// Grouped GEMM, round 11: 128m x 128n, 8 waves (512 thr), 2-PHASE double-
// buffered, 64 KB LDS.
//
// Round-3 closed the A/B matrix:
//   1-phase@16 waves/CU (r0, r3)  ~39us  |  2-phase@8 waves/CU (r2)  ~40us
// i.e. 2-phase at HALF the waves matched 1-phase at full waves -> intra-block
// prefetch is worth ~2x in wave-equivalents; r2 spent the gain on occupancy.
// Pipelining and TLP are ADDITIVE currencies; this round is the untested
// cell: BOTH. 64 KB double-buffer at 512 threads -> 160//64 = 2 blocks/CU =
// 16 waves/CU in 2 independent barrier groups, AND STAGE(next) issued ~200cy
// of ds_read+MFMA before the draining barrier. Per-SIMD issue work
// (4 waves x ~208cy) > ~600cy gather latency -> near-full hiding.
//
// Loop invariants (unchanged, validated r2/r3): stage rows ≡ rsub (mod 8);
// read XOR key = row&7; barrier-per-iter is race-free (STAGE targets nxt,
// cur is only overwritten after the barrier that follows its last read).
// Expert->XCD pinning kept (e = gid&7).
//
// Epilogue: bf16 stores into slot buffer packed in d_out's y region:
// token t's 4 KiB = [buf0[t] | buf1[t]].
// ---------------------------------------------------------------------------
__global__ __launch_bounds__(512)
void moe_gemm(const __bf16* __restrict__ xb, const __bf16* __restrict__ Wt,
              const int* __restrict__ cnt, const int* __restrict__ perm,
              __bf16* __restrict__ buf) {
  const int gid = blockIdx.x;
  const int e   = gid & 7;
  const int n0  = ((gid >> 3) & 7) * 128;
  const int m0  = (gid >> 6) * 128;
  const int count = cnt[e];
  if (m0 >= count) return;

  const int*    permE = perm + e * CAP;
  const __bf16* We    = Wt + (size_t)e * C_DIM * C_DIM;

  // [2 bufs][ A: 128x128B | B: 128x128B ] = 64 KB
  __shared__ __align__(16) char smem[65536];

  const int tid  = threadIdx.x;
  const int lane = tid & 63;
  const int wv   = tid >> 6;                 // 0..7
  const int wr = wv >> 1, wc = wv & 1;       // wave tile: rows wr*32, cols wc*64
  const int l32 = lane & 31, hi = lane >> 5;

  const int rsub  = lane >> 3;          // 0..7
  const int chunk = (lane & 7) ^ rsub;  // XOR swizzle key = row&7

  // staging ownership: wave wv stages A rows [wv*16, wv*16+16) and
  // B rows [wv*16, wv*16+16), 8 rows per GLD16 (q=0..1 each).
  int tk[2];
#pragma unroll
  for (int q = 0; q < 2; ++q) {
    const int i = m0 + wv * 16 + q * 8 + rsub;
    tk[q] = (i < count) ? (permE[i] >> 1) : 0;
  }
  const char* gA = (const char*)xb;     // + tk*2048 + kb + chunk*16
  const char* gB = (const char*)We + (size_t)(n0 + wv * 16 + rsub) * 2048 +
                   chunk * 16;          // + q*8*2048 + kb

  f32x16 acc[2];
#pragma unroll
  for (int ng = 0; ng < 2; ++ng)
#pragma unroll
    for (int r = 0; r < 16; ++r) acc[ng][r] = 0.f;

#define STAGE(bufsel, kb)                                                    \
  do {                                                                       \
    char* lA = smem + (bufsel) * 32768 + (wv * 16) * 128;                    \
    char* lB = lA + 16384;                                                   \
    _Pragma("unroll")                                                        \
    for (int q = 0; q < 2; ++q)                                              \
      GLD16(gA + (size_t)tk[q] * 2048 + (kb) + chunk * 16, lA + q * 1024);   \
    _Pragma("unroll")                                                        \
    for (int q = 0; q < 2; ++q)                                              \
      GLD16(gB + (size_t)q * 8 * 2048 + (kb), lB + q * 1024);                \
  } while (0)

  // prologue: stage k-tile 0 into buffer 0
  STAGE(0, 0);
  __syncthreads();   // vmcnt(0)+lgkmcnt(0) drain: buffer 0 ready

  int cur = 0;
  for (int kt = 0; kt < 16; ++kt) {
    const int nxt = cur ^ 1;
    if (kt < 15) STAGE(nxt, (kt + 1) * 128);  // issue before compute (T3)

    const char* Ab = smem + cur * 32768;
    const char* Bb = Ab + 16384;
#pragma unroll
    for (int ks = 0; ks < 4; ++ks) {
      const int c = ks * 2 + hi;        // 16B chunk index along the 128B row
      const int rA = wr * 32 + l32;
      const bf16x8 af = *(const bf16x8*)(Ab + rA * 128 + ((c ^ (rA & 7)) << 4));
      bf16x8 bfr[2];
#pragma unroll
      for (int ng = 0; ng < 2; ++ng) {
        const int rB = wc * 64 + ng * 32 + l32;
        bfr[ng] = *(const bf16x8*)(Bb + rB * 128 + ((c ^ (rB & 7)) << 4));
      }
#pragma unroll
      for (int ng = 0; ng < 2; ++ng)
        acc[ng] = __builtin_amdgcn_mfma_f32_32x32x16_bf16(af, bfr[ng], acc[ng], 0, 0, 0);
    }
    __syncthreads();  // drains vmcnt(0): nxt ready; all waves done reading cur
    cur = nxt;
  }
#undef STAGE

  // epilogue: C/D row=(reg&3)+8*(reg>>2)+4*hi, col=l32 (validated round 6)
#pragma unroll
  for (int r = 0; r < 16; ++r) {
    const int row = (r & 3) + 8 * (r >> 2) + 4 * hi;
    const int i = m0 + wr * 32 + row;
    if (i < count) {
      const int pe = permE[i];
      __bf16* orow = buf + (size_t)(pe >> 1) * 2048 + (pe & 1) * 1024 +
                     n0 + wc * 64 + l32;
      orow[0]  = (__bf16)acc[0][r];
      orow[32] = (__bf16)acc[1][r];
    }
  }
}

// ---------------------------------------------------------------------------
// Combine, IN PLACE: block t owns y[t]'s 4 KiB = [buf0[t] | buf1[t]] bf16.
// Load both halves, barrier (drains vmcnt), overwrite with fp32 y.
// ---------------------------------------------------------------------------
__global__ __launch_bounds__(256)
void combine(const float* __restrict__ probs, float* __restrict__ y) {
  const int t = blockIdx.x;
  const int c = threadIdx.x * 4;
  const __bf16* bt = (const __bf16*)(y + (size_t)t * C_DIM);
  const bf16x4v b0 = *(const bf16x4v*)(bt + c);
  const bf16x4v b1 = *(const bf16x4v*)(bt + 1024 + c);
  const float p0 = probs[2 * t], p1 = probs[2 * t + 1];
  __syncthreads();   // all reads of this block's region complete before writes
  float4 o = { p0 * (float)b0[0] + p1 * (float)b1[0],
               p0 * (float)b0[1] + p1 * (float)b1[1],
               p0 * (float)b0[2] + p1 * (float)b1[2],
               p0 * (float)b0[3] + p1 * (float)b1[3] };
  *(float4*)(y + (size_t)t * C_DIM + c) = o;
}

extern "C" void kernel_launch(void* const* d_in, const int* in_sizes, int n_in,
                              void* d_out, int out_size, void* d_ws, size_t ws_size,
                              hipStream_t stream) {
  const float* x    = (const float*)d_in[0];
  const float* wg   = (const float*)d_in[1];
  const float* bias = (const float*)d_in[2];
  const float* wcfc = (const float*)d_in[3];

  float* y     = (float*)d_out;
  float* probs = y + (size_t)N_TOK * C_DIM;
  __bf16* buf  = (__bf16*)d_out;         // slot buffers packed in y region

  char* ws   = (char*)d_ws;
  int*    cnt  = (int*)(ws + WS_CNT);
  int*    perm = (int*)(ws + WS_PERM);
  __bf16* xb   = (__bf16*)(ws + WS_XB);
  __bf16* Wt   = (__bf16*)(ws + WS_WT);

  hipMemsetAsync(cnt, 0, N_EXP * sizeof(int), stream);

  prep_kernel<<<256 + 8192, 256, 0, stream>>>(x, wg, bias, wcfc, xb, probs,
                                              Wt, cnt, perm);
  // 8 experts x 8 n-blocks x up to 32 m-blocks (CAP/128); early-exit on count
  moe_gemm<<<8 * 8 * 32, 512, 0, stream>>>(xb, Wt, cnt, perm, buf);
  combine<<<N_TOK, 256, 0, stream>>>(probs, y);
}

// Round 5
// 140.439 us; speedup vs baseline: 1.0140x; 1.0140x over previous
//
#include <hip/hip_runtime.h>
#include <math.h>

typedef __attribute__((ext_vector_type(8))) __bf16 bf16x8;
typedef __attribute__((ext_vector_type(4))) __bf16 bf16x4v;
typedef __attribute__((ext_vector_type(2))) __bf16 bf16x2;
typedef __attribute__((ext_vector_type(16))) float f32x16;

#define N_TOK  4096
#define C_DIM  1024
#define N_EXP  8
#define CAP    4096

// workspace layout (bytes). ws_size ~= 256 MiB (poison-fill WRITE_SIZE evidence).
// NOTE round-3 postmortem: '<<' binds looser than '+' — keep offsets parenthesized.
#define WS_CNT    0                                   // 32 B
#define WS_PERM   32768                               // 128 KB: per-expert slot lists
#define WS_XB     ((size_t)1 << 20)                   // 8 MB: x in bf16
#define WS_WT     (WS_XB + ((size_t)8 << 20))         // 16 MB: W^T bf16

// async global->LDS, 16B per lane. LDS dest is wave-uniform base + lane*16.
#define GLD16(g, l)                                                        \
  __builtin_amdgcn_global_load_lds(                                        \
      (const __attribute__((address_space(1))) void*)(g),                  \
      (__attribute__((address_space(3))) void*)(l), 16, 0, 0)

// ---------------------------------------------------------------------------
// prep: fused router (blocks 0..255) + W transpose/bf16 (blocks 256..767).
//
// Round-5 rewrite of the transpose (the round-4 postmortem's lever): the old
// version was 8192 tiny 32x32 blocks with SCALAR f32 loads and SCALAR bf16
// stores in 64 B segments — the classic G13 2-2.5x penalty on the largest
// traffic component (144 MB of W read + Wt write). New: 512 blocks, 128x128
// tile each. Read: float4 x2 adjacent rows (512 B wave segments), pack
// vertical bf16 pairs -> u32 LDS scatter [o][ipair] (+4-u32 row pad keeps
// 16 B alignment; ~8-way write conflicts are ~6x under the HBM time, left
// unswizzled). Write: ds_read_b128 -> 16 B global stores, 256 B segments.
// Router unchanged.
// ---------------------------------------------------------------------------
__global__ __launch_bounds__(256)
void prep_kernel(const float* __restrict__ x, const float* __restrict__ wg,
                 const float* __restrict__ bias, const float* __restrict__ W,
                 __bf16* __restrict__ xb, float* __restrict__ probs,
                 __bf16* __restrict__ Wt, int* __restrict__ cnt,
                 int* __restrict__ perm) {
  __shared__ __align__(16) char smem[34816];   // max(32 KB router, 128*68*4 B)
  __shared__ int lcnt[N_EXP], base[N_EXP];
  const int tid = threadIdx.x;

  if (blockIdx.x < 256) {
    // ---------------- router ----------------
    float (*wgT)[C_DIM] = (float (*)[C_DIM])smem;   // [N_EXP][C_DIM], 32 KB
    if (tid < N_EXP) lcnt[tid] = 0;

#pragma unroll
    for (int i = 0; i < 8; ++i) {
      const float4 v = ((const float4*)wg)[i * 256 + tid];
      const int f = (i * 256 + tid) * 4;
      const int c = f >> 3;
      const int e = f & 7;
      wgT[e][c] = v.x; wgT[e + 1][c] = v.y; wgT[e + 2][c] = v.z; wgT[e + 3][c] = v.w;
    }
    __syncthreads();

    const int lane = tid & 63;
    const int wv   = tid >> 6;
    int re0[4], re1[4], rs0[4], rs1[4];   // lane0-valid per s

#pragma unroll
    for (int s = 0; s < 4; ++s) {
      const int t = blockIdx.x * 16 + wv * 4 + s;
      const float4* xrow = (const float4*)(x + (size_t)t * C_DIM);
      float acc[N_EXP];
#pragma unroll
      for (int e = 0; e < N_EXP; ++e) acc[e] = 0.f;

#pragma unroll
      for (int j = 0; j < 4; ++j) {
        const int c4 = j * 64 + lane;
        const float4 v = xrow[c4];
        bf16x4v bv = { (__bf16)v.x, (__bf16)v.y, (__bf16)v.z, (__bf16)v.w };
        *(bf16x4v*)(xb + (size_t)t * C_DIM + c4 * 4) = bv;
#pragma unroll
        for (int e = 0; e < N_EXP; ++e) {
          const float4 w = *(const float4*)&wgT[e][c4 * 4];
          acc[e] += v.x * w.x + v.y * w.y + v.z * w.z + v.w * w.w;
        }
      }

#pragma unroll
      for (int off = 32; off >= 1; off >>= 1) {
#pragma unroll
        for (int e = 0; e < N_EXP; ++e) acc[e] += __shfl_xor(acc[e], off, 64);
      }

      if (lane == 0) {
        float l[N_EXP];
#pragma unroll
        for (int e = 0; e < N_EXP; ++e) l[e] = acc[e] + bias[e];
        int e0 = 0;
#pragma unroll
        for (int e = 1; e < N_EXP; ++e) if (l[e] > l[e0]) e0 = e;
        int e1 = (e0 == 0) ? 1 : 0;
#pragma unroll
        for (int e = 0; e < N_EXP; ++e) if (e != e0 && l[e] > l[e1]) e1 = e;
        const float p0 = 1.f / (1.f + expf(l[e1] - l[e0]));
        probs[t * 2]     = p0;
        probs[t * 2 + 1] = 1.f - p0;
        re0[s] = e0; re1[s] = e1;
        rs0[s] = atomicAdd(&lcnt[e0], 1);
        rs1[s] = atomicAdd(&lcnt[e1], 1);
      }
    }
    __syncthreads();
    if (tid < N_EXP) base[tid] = atomicAdd(&cnt[tid], lcnt[tid]);
    __syncthreads();
    if (lane == 0) {
#pragma unroll
      for (int s = 0; s < 4; ++s) {
        const int t = blockIdx.x * 16 + wv * 4 + s;
        perm[re0[s] * CAP + base[re0[s]] + rs0[s]] = t * 2;
        perm[re1[s] * CAP + base[re1[s]] + rs1[s]] = t * 2 + 1;
      }
    }
  } else {
    // ---------------- W transpose + bf16 convert, 128x128 tiles ----------------
    // LDS layout: [128 o-rows][68 u32] (64 used + 4 pad -> 272 B stride, 16 B
    // aligned). u32 = bf16 pair (W[i][o], W[i+1][o]) = Wt[o][i..i+1].
    bf16x2 (*l)[68] = (bf16x2 (*)[68])smem;
    const int b  = blockIdx.x - 256;
    const int e  = b >> 6;
    const int r  = b & 63;
    const int i0 = (r >> 3) * 128;
    const int o0 = (r & 7) * 128;
    const float* We  = W  + (size_t)e * C_DIM * C_DIM;
    __bf16*      Wte = Wt + (size_t)e * C_DIM * C_DIM;

    // read phase: 2048 (ip,c) pairs; ip = i-pair 0..63, c = o-quad 0..31.
#pragma unroll
    for (int it = 0; it < 8; ++it) {
      const int idx = it * 256 + tid;
      const int ip  = idx >> 5;          // 0..63
      const int c   = idx & 31;          // 0..31
      const float4 va = *(const float4*)(We + (size_t)(i0 + 2 * ip)     * C_DIM + o0 + 4 * c);
      const float4 vb = *(const float4*)(We + (size_t)(i0 + 2 * ip + 1) * C_DIM + o0 + 4 * c);
      l[4 * c + 0][ip] = bf16x2{ (__bf16)va.x, (__bf16)vb.x };
      l[4 * c + 1][ip] = bf16x2{ (__bf16)va.y, (__bf16)vb.y };
      l[4 * c + 2][ip] = bf16x2{ (__bf16)va.z, (__bf16)vb.z };
      l[4 * c + 3][ip] = bf16x2{ (__bf16)va.w, (__bf16)vb.w };
    }
    __syncthreads();

    // write phase: 2048 (o,k) chunks; o = 0..127, k = 0..15 (8 bf16 each).
#pragma unroll
    for (int it = 0; it < 8; ++it) {
      const int idx = it * 256 + tid;
      const int o   = idx >> 4;          // 0..127
      const int k   = idx & 15;          // 0..15
      const bf16x8 v = *(const bf16x8*)&l[o][4 * k];
      *(bf16x8*)(Wte + (size_t)(o0 + o) * C_DIM + i0 + 8 * k) = v;
    }
  }
}

// ---------------------------------------------------------------------------
// Grouped GEMM (FROZEN at round-10/round-3 structure — best measured, 4
// schedule variants all within/worse than noise): 128m x 128n tile, 8 waves
// (512 thr), 1-phase single-buffered, 32 KB LDS -> 2 blocks/CU = 16 waves/CU
// in 2 independent barrier groups. Schedule matrix closed r0-r4: 1ph/16w ~39us
// beats 2ph in all tested occupancy configs (prefetch queue pressure + LDS
// footprint cost more than they hide at this gather latency).
// Swizzle invariant: stage rows ≡ rsub (mod 8); read XOR key = row&7.
// Expert->XCD pinning (e = gid&7).
// Epilogue: bf16 stores into slot buffer packed in d_out's y region:
// token t's 4 KiB = [buf0[t] | buf1[t]].
// ---------------------------------------------------------------------------
__global__ __launch_bounds__(512)
void moe_gemm(const __bf16* __restrict__ xb, const __bf16* __restrict__ Wt,
              const int* __restrict__ cnt, const int* __restrict__ perm,
              __bf16* __restrict__ buf) {
  const int gid = blockIdx.x;
  const int e   = gid & 7;
  const int n0  = ((gid >> 3) & 7) * 128;
  const int m0  = (gid >> 6) * 128;
  const int count = cnt[e];
  if (m0 >= count) return;

  const int*    permE = perm + e * CAP;
  const __bf16* We    = Wt + (size_t)e * C_DIM * C_DIM;

  // [ A: 128 rows x 128 B | B: 128 rows x 128 B ] = 32 KB, single buffer
  __shared__ __align__(16) char smem[32768];

  const int tid  = threadIdx.x;
  const int lane = tid & 63;
  const int wv   = tid >> 6;                 // 0..7
  const int wr = wv >> 1, wc = wv & 1;       // wave tile: rows wr*32, cols wc*64
  const int l32 = lane & 31, hi = lane >> 5;

  const int rsub  = lane >> 3;          // 0..7
  const int chunk = (lane & 7) ^ rsub;  // XOR swizzle key = row&7

  // staging ownership: wave wv stages A rows [wv*16, wv*16+16) and
  // B rows [wv*16, wv*16+16), 8 rows per GLD16 (q=0..1 each).
  int tk[2];
#pragma unroll
  for (int q = 0; q < 2; ++q) {
    const int i = m0 + wv * 16 + q * 8 + rsub;
    tk[q] = (i < count) ? (permE[i] >> 1) : 0;
  }
  const char* gA = (const char*)xb;     // + tk*2048 + kb + chunk*16
  const char* gB = (const char*)We + (size_t)(n0 + wv * 16 + rsub) * 2048 +
                   chunk * 16;          // + q*8*2048 + kb

  f32x16 acc[2];
#pragma unroll
  for (int ng = 0; ng < 2; ++ng)
#pragma unroll
    for (int r = 0; r < 16; ++r) acc[ng][r] = 0.f;

  for (int kt = 0; kt < 16; ++kt) {
    const int kb = kt * 128;   // byte offset along K (64 bf16)
    {
      char* lA = smem + (wv * 16) * 128;          // A region base
      char* lB = smem + 16384 + (wv * 16) * 128;  // B region base
#pragma unroll
      for (int q = 0; q < 2; ++q)
        GLD16(gA + (size_t)tk[q] * 2048 + kb + chunk * 16, lA + q * 1024);
#pragma unroll
      for (int q = 0; q < 2; ++q)
        GLD16(gB + (size_t)q * 8 * 2048 + kb, lB + q * 1024);
    }
    __syncthreads();   // vmcnt(0)+lgkmcnt(0): tile ready

#pragma unroll
    for (int ks = 0; ks < 4; ++ks) {
      const int c = ks * 2 + hi;        // 16B chunk index along the 128B row
      const int rA = wr * 32 + l32;
      const bf16x8 af = *(const bf16x8*)(smem + rA * 128 + ((c ^ (rA & 7)) << 4));
      bf16x8 bfr[2];
#pragma unroll
      for (int ng = 0; ng < 2; ++ng) {
        const int rB = wc * 64 + ng * 32 + l32;
        bfr[ng] = *(const bf16x8*)(smem + 16384 + rB * 128 + ((c ^ (rB & 7)) << 4));
      }
#pragma unroll
      for (int ng = 0; ng < 2; ++ng)
        acc[ng] = __builtin_amdgcn_mfma_f32_32x32x16_bf16(af, bfr[ng], acc[ng], 0, 0, 0);
    }
    __syncthreads();   // all waves done reading before next stage overwrites
  }

  // epilogue: C/D row=(reg&3)+8*(reg>>2)+4*hi, col=l32 (validated round 6)
#pragma unroll
  for (int r = 0; r < 16; ++r) {
    const int row = (r & 3) + 8 * (r >> 2) + 4 * hi;
    const int i = m0 + wr * 32 + row;
    if (i < count) {
      const int pe = permE[i];
      __bf16* orow = buf + (size_t)(pe >> 1) * 2048 + (pe & 1) * 1024 +
                     n0 + wc * 64 + l32;
      orow[0]  = (__bf16)acc[0][r];
      orow[32] = (__bf16)acc[1][r];
    }
  }
}

// ---------------------------------------------------------------------------
// Combine, IN PLACE: block t owns y[t]'s 4 KiB = [buf0[t] | buf1[t]] bf16.
// Load both halves, barrier (drains vmcnt), overwrite with fp32 y.
// ---------------------------------------------------------------------------
__global__ __launch_bounds__(256)
void combine(const float* __restrict__ probs, float* __restrict__ y) {
  const int t = blockIdx.x;
  const int c = threadIdx.x * 4;
  const __bf16* bt = (const __bf16*)(y + (size_t)t * C_DIM);
  const bf16x4v b0 = *(const bf16x4v*)(bt + c);
  const bf16x4v b1 = *(const bf16x4v*)(bt + 1024 + c);
  const float p0 = probs[2 * t], p1 = probs[2 * t + 1];
  __syncthreads();   // all reads of this block's region complete before writes
  float4 o = { p0 * (float)b0[0] + p1 * (float)b1[0],
               p0 * (float)b0[1] + p1 * (float)b1[1],
               p0 * (float)b0[2] + p1 * (float)b1[2],
               p0 * (float)b0[3] + p1 * (float)b1[3] };
  *(float4*)(y + (size_t)t * C_DIM + c) = o;
}

extern "C" void kernel_launch(void* const* d_in, const int* in_sizes, int n_in,
                              void* d_out, int out_size, void* d_ws, size_t ws_size,
                              hipStream_t stream) {
  const float* x    = (const float*)d_in[0];
  const float* wg   = (const float*)d_in[1];
  const float* bias = (const float*)d_in[2];
  const float* wcfc = (const float*)d_in[3];

  float* y     = (float*)d_out;
  float* probs = y + (size_t)N_TOK * C_DIM;
  __bf16* buf  = (__bf16*)d_out;         // slot buffers packed in y region

  char* ws   = (char*)d_ws;
  int*    cnt  = (int*)(ws + WS_CNT);
  int*    perm = (int*)(ws + WS_PERM);
  __bf16* xb   = (__bf16*)(ws + WS_XB);
  __bf16* Wt   = (__bf16*)(ws + WS_WT);

  hipMemsetAsync(cnt, 0, N_EXP * sizeof(int), stream);

  prep_kernel<<<256 + 512, 256, 0, stream>>>(x, wg, bias, wcfc, xb, probs,
                                             Wt, cnt, perm);
  // 8 experts x 8 n-blocks x up to 32 m-blocks (CAP/128); early-exit on count
  moe_gemm<<<8 * 8 * 32, 512, 0, stream>>>(xb, Wt, cnt, perm, buf);
  combine<<<N_TOK, 256, 0, stream>>>(probs, y);
}

// Round 6
// 138.016 us; speedup vs baseline: 1.0318x; 1.0176x over previous
//
#include <hip/hip_runtime.h>
#include <math.h>

typedef __attribute__((ext_vector_type(8))) __bf16 bf16x8;
typedef __attribute__((ext_vector_type(4))) __bf16 bf16x4v;
typedef __attribute__((ext_vector_type(16))) float f32x16;

#define N_TOK  4096
#define C_DIM  1024
#define N_EXP  8
#define CAP    4096

// workspace layout (bytes). ws_size ~= 256 MiB (poison-fill WRITE_SIZE evidence).
// NOTE round-3 postmortem: '<<' binds looser than '+' — keep offsets parenthesized.
#define WS_CNT    0                                   // 32 B
#define WS_PERM   32768                               // 128 KB: per-expert slot lists
#define WS_XB     ((size_t)1 << 20)                   // 8 MB: x in bf16
#define WS_WT     (WS_XB + ((size_t)8 << 20))         // 16 MB: W^T bf16

// async global->LDS, 16B per lane. LDS dest is wave-uniform base + lane*16.
#define GLD16(g, l)                                                        \
  __builtin_amdgcn_global_load_lds(                                        \
      (const __attribute__((address_space(1))) void*)(g),                  \
      (__attribute__((address_space(3))) void*)(l), 16, 0, 0)

// ---------------------------------------------------------------------------
// prep: fused router (blocks 0..255) + W transpose/bf16 (blocks 256..767).
//
// Transpose v3 (round 6). History: v1 (r0-r4) = 8192 tiny 32x32 blocks,
// scalar 2 B stores in 64 B segments, latency-bound => ~35 us. v2 (r5) =
// vectorized but the LDS pack-write l[4c+j][ip] (68-u32 stride) put 32 lanes
// on 2 banks (stride 272 ≡ 16 mod 32 -> 16-way conflict) => no gain.
// v3 is designed by bank arithmetic:
//   - stage 128x128 f32 tile via GLD16 (async, no VGPR path), linear 512 B
//     rows, 16 B-chunk XOR swizzle on the GLOBAL SOURCE, key=(row>>3)&7
//     (both-sides-or-neither rule);
//   - read: thread (oct,o) reads 8 col values; bank = 4*((o>>2)^(oct&7))
//     + (o&3): 16 octs -> 8 banks x2 (2-way = free), 4 quarter-waves in
//     disjoint bank classes -> exactly 2 lanes/bank full-wave;
//   - write: quarter-wave = 16 x bf16x8 = 256 B contiguous Wt segment.
// Counters live at smem+32768 (router uses 32 KB; transpose all 64 KB).
// Router unchanged.
// ---------------------------------------------------------------------------
__global__ __launch_bounds__(256)
void prep_kernel(const float* __restrict__ x, const float* __restrict__ wg,
                 const float* __restrict__ bias, const float* __restrict__ W,
                 __bf16* __restrict__ xb, float* __restrict__ probs,
                 __bf16* __restrict__ Wt, int* __restrict__ cnt,
                 int* __restrict__ perm) {
  __shared__ __align__(16) char smem[65536];
  int* lcnt = (int*)(smem + 32768);   // router-only (transpose overwrites)
  int* base = lcnt + N_EXP;
  const int tid = threadIdx.x;

  if (blockIdx.x < 256) {
    // ---------------- router ----------------
    float (*wgT)[C_DIM] = (float (*)[C_DIM])smem;   // [N_EXP][C_DIM], 32 KB
    if (tid < N_EXP) lcnt[tid] = 0;

#pragma unroll
    for (int i = 0; i < 8; ++i) {
      const float4 v = ((const float4*)wg)[i * 256 + tid];
      const int f = (i * 256 + tid) * 4;
      const int c = f >> 3;
      const int e = f & 7;
      wgT[e][c] = v.x; wgT[e + 1][c] = v.y; wgT[e + 2][c] = v.z; wgT[e + 3][c] = v.w;
    }
    __syncthreads();

    const int lane = tid & 63;
    const int wv   = tid >> 6;
    int re0[4], re1[4], rs0[4], rs1[4];   // lane0-valid per s

#pragma unroll
    for (int s = 0; s < 4; ++s) {
      const int t = blockIdx.x * 16 + wv * 4 + s;
      const float4* xrow = (const float4*)(x + (size_t)t * C_DIM);
      float acc[N_EXP];
#pragma unroll
      for (int e = 0; e < N_EXP; ++e) acc[e] = 0.f;

#pragma unroll
      for (int j = 0; j < 4; ++j) {
        const int c4 = j * 64 + lane;
        const float4 v = xrow[c4];
        bf16x4v bv = { (__bf16)v.x, (__bf16)v.y, (__bf16)v.z, (__bf16)v.w };
        *(bf16x4v*)(xb + (size_t)t * C_DIM + c4 * 4) = bv;
#pragma unroll
        for (int e = 0; e < N_EXP; ++e) {
          const float4 w = *(const float4*)&wgT[e][c4 * 4];
          acc[e] += v.x * w.x + v.y * w.y + v.z * w.z + v.w * w.w;
        }
      }

#pragma unroll
      for (int off = 32; off >= 1; off >>= 1) {
#pragma unroll
        for (int e = 0; e < N_EXP; ++e) acc[e] += __shfl_xor(acc[e], off, 64);
      }

      if (lane == 0) {
        float l[N_EXP];
#pragma unroll
        for (int e = 0; e < N_EXP; ++e) l[e] = acc[e] + bias[e];
        int e0 = 0;
#pragma unroll
        for (int e = 1; e < N_EXP; ++e) if (l[e] > l[e0]) e0 = e;
        int e1 = (e0 == 0) ? 1 : 0;
#pragma unroll
        for (int e = 0; e < N_EXP; ++e) if (e != e0 && l[e] > l[e1]) e1 = e;
        const float p0 = 1.f / (1.f + expf(l[e1] - l[e0]));
        probs[t * 2]     = p0;
        probs[t * 2 + 1] = 1.f - p0;
        re0[s] = e0; re1[s] = e1;
        rs0[s] = atomicAdd(&lcnt[e0], 1);
        rs1[s] = atomicAdd(&lcnt[e1], 1);
      }
    }
    __syncthreads();
    if (tid < N_EXP) base[tid] = atomicAdd(&cnt[tid], lcnt[tid]);
    __syncthreads();
    if (lane == 0) {
#pragma unroll
      for (int s = 0; s < 4; ++s) {
        const int t = blockIdx.x * 16 + wv * 4 + s;
        perm[re0[s] * CAP + base[re0[s]] + rs0[s]] = t * 2;
        perm[re1[s] * CAP + base[re1[s]] + rs1[s]] = t * 2 + 1;
      }
    }
  } else {
    // ---------------- W transpose + bf16 convert, 128x128 f32 tile ----------
    const int b  = blockIdx.x - 256;
    const int e  = b >> 6;
    const int r  = b & 63;
    const int i0 = (r >> 3) * 128;
    const int o0 = (r & 7) * 128;
    const float* We  = W  + (size_t)e * C_DIM * C_DIM;
    __bf16*      Wte = Wt + (size_t)e * C_DIM * C_DIM;
    const float* lds = (const float*)smem;   // [128 rows][128 f32], rows 512 B
    const int l  = tid & 63;
    const int w  = tid >> 6;                 // wave 0..3 owns rows w*32..+31
    const int rl = l >> 5;                   // row within the GLD16 pair
    const int c  = l & 31;                   // 16 B chunk position in row

    // stage: 16 GLD16/wave, 2 rows (1 KB) each; source chunk XOR-swizzled.
#pragma unroll
    for (int g = 0; g < 16; ++g) {
      const int row = w * 32 + g * 2 + rl;
      const int key = (row >> 3) & 7;
      GLD16((const char*)(We + (size_t)(i0 + row) * C_DIM + o0) +
                ((c ^ key) << 4),
            smem + (w * 32 + g * 2) * 512);
    }
    __syncthreads();

    // write: 8 units/thread; unit = (o 0..127, oct 0..15); 8 col-reads
    // (conflict-free per bank math above), cvt, one 16 B store.
#pragma unroll
    for (int u = 0; u < 8; ++u) {
      const int unit = u * 256 + tid;
      const int oct  = unit & 15;
      const int o    = unit >> 4;
      const int chk  = ((o >> 2) ^ (oct & 7)) << 2;
      bf16x8 pk;
#pragma unroll
      for (int j = 0; j < 8; ++j)
        pk[j] = (__bf16)lds[(oct * 8 + j) * 128 + chk + (o & 3)];
      *(bf16x8*)(Wte + (size_t)(o0 + o) * C_DIM + i0 + oct * 8) = pk;
    }
  }
}

// ---------------------------------------------------------------------------
// Grouped GEMM (FROZEN at round-10/round-3 structure — best measured; the
// r0-r4 schedule matrix closed: 1ph/16w ~39us beats 2ph at every occupancy).
// 128m x 128n tile, 8 waves (512 thr), 1-phase single-buffered, 32 KB LDS ->
// 2 blocks/CU = 16 waves/CU in 2 independent barrier groups.
// Swizzle invariant: stage rows ≡ rsub (mod 8); read XOR key = row&7.
// Expert->XCD pinning (e = gid&7).
// Epilogue: bf16 stores into slot buffer packed in d_out's y region:
// token t's 4 KiB = [buf0[t] | buf1[t]].
// ---------------------------------------------------------------------------
__global__ __launch_bounds__(512)
void moe_gemm(const __bf16* __restrict__ xb, const __bf16* __restrict__ Wt,
              const int* __restrict__ cnt, const int* __restrict__ perm,
              __bf16* __restrict__ buf) {
  const int gid = blockIdx.x;
  const int e   = gid & 7;
  const int n0  = ((gid >> 3) & 7) * 128;
  const int m0  = (gid >> 6) * 128;
  const int count = cnt[e];
  if (m0 >= count) return;

  const int*    permE = perm + e * CAP;
  const __bf16* We    = Wt + (size_t)e * C_DIM * C_DIM;

  // [ A: 128 rows x 128 B | B: 128 rows x 128 B ] = 32 KB, single buffer
  __shared__ __align__(16) char smem[32768];

  const int tid  = threadIdx.x;
  const int lane = tid & 63;
  const int wv   = tid >> 6;                 // 0..7
  const int wr = wv >> 1, wc = wv & 1;       // wave tile: rows wr*32, cols wc*64
  const int l32 = lane & 31, hi = lane >> 5;

  const int rsub  = lane >> 3;          // 0..7
  const int chunk = (lane & 7) ^ rsub;  // XOR swizzle key = row&7

  // staging ownership: wave wv stages A rows [wv*16, wv*16+16) and
  // B rows [wv*16, wv*16+16), 8 rows per GLD16 (q=0..1 each).
  int tk[2];
#pragma unroll
  for (int q = 0; q < 2; ++q) {
    const int i = m0 + wv * 16 + q * 8 + rsub;
    tk[q] = (i < count) ? (permE[i] >> 1) : 0;
  }
  const char* gA = (const char*)xb;     // + tk*2048 + kb + chunk*16
  const char* gB = (const char*)We + (size_t)(n0 + wv * 16 + rsub) * 2048 +
                   chunk * 16;          // + q*8*2048 + kb

  f32x16 acc[2];
#pragma unroll
  for (int ng = 0; ng < 2; ++ng)
#pragma unroll
    for (int r = 0; r < 16; ++r) acc[ng][r] = 0.f;

  for (int kt = 0; kt < 16; ++kt) {
    const int kb = kt * 128;   // byte offset along K (64 bf16)
    {
      char* lA = smem + (wv * 16) * 128;          // A region base
      char* lB = smem + 16384 + (wv * 16) * 128;  // B region base
#pragma unroll
      for (int q = 0; q < 2; ++q)
        GLD16(gA + (size_t)tk[q] * 2048 + kb + chunk * 16, lA + q * 1024);
#pragma unroll
      for (int q = 0; q < 2; ++q)
        GLD16(gB + (size_t)q * 8 * 2048 + kb, lB + q * 1024);
    }
    __syncthreads();   // vmcnt(0)+lgkmcnt(0): tile ready

#pragma unroll
    for (int ks = 0; ks < 4; ++ks) {
      const int c = ks * 2 + hi;        // 16B chunk index along the 128B row
      const int rA = wr * 32 + l32;
      const bf16x8 af = *(const bf16x8*)(smem + rA * 128 + ((c ^ (rA & 7)) << 4));
      bf16x8 bfr[2];
#pragma unroll
      for (int ng = 0; ng < 2; ++ng) {
        const int rB = wc * 64 + ng * 32 + l32;
        bfr[ng] = *(const bf16x8*)(smem + 16384 + rB * 128 + ((c ^ (rB & 7)) << 4));
      }
#pragma unroll
      for (int ng = 0; ng < 2; ++ng)
        acc[ng] = __builtin_amdgcn_mfma_f32_32x32x16_bf16(af, bfr[ng], acc[ng], 0, 0, 0);
    }
    __syncthreads();   // all waves done reading before next stage overwrites
  }

  // epilogue: C/D row=(reg&3)+8*(reg>>2)+4*hi, col=l32 (validated round 6)
#pragma unroll
  for (int r = 0; r < 16; ++r) {
    const int row = (r & 3) + 8 * (r >> 2) + 4 * hi;
    const int i = m0 + wr * 32 + row;
    if (i < count) {
      const int pe = permE[i];
      __bf16* orow = buf + (size_t)(pe >> 1) * 2048 + (pe & 1) * 1024 +
                     n0 + wc * 64 + l32;
      orow[0]  = (__bf16)acc[0][r];
      orow[32] = (__bf16)acc[1][r];
    }
  }
}

// ---------------------------------------------------------------------------
// Combine, IN PLACE: block t owns y[t]'s 4 KiB = [buf0[t] | buf1[t]] bf16.
// Load both halves, barrier (drains vmcnt), overwrite with fp32 y.
// ---------------------------------------------------------------------------
__global__ __launch_bounds__(256)
void combine(const float* __restrict__ probs, float* __restrict__ y) {
  const int t = blockIdx.x;
  const int c = threadIdx.x * 4;
  const __bf16* bt = (const __bf16*)(y + (size_t)t * C_DIM);
  const bf16x4v b0 = *(const bf16x4v*)(bt + c);
  const bf16x4v b1 = *(const bf16x4v*)(bt + 1024 + c);
  const float p0 = probs[2 * t], p1 = probs[2 * t + 1];
  __syncthreads();   // all reads of this block's region complete before writes
  float4 o = { p0 * (float)b0[0] + p1 * (float)b1[0],
               p0 * (float)b0[1] + p1 * (float)b1[1],
               p0 * (float)b0[2] + p1 * (float)b1[2],
               p0 * (float)b0[3] + p1 * (float)b1[3] };
  *(float4*)(y + (size_t)t * C_DIM + c) = o;
}

extern "C" void kernel_launch(void* const* d_in, const int* in_sizes, int n_in,
                              void* d_out, int out_size, void* d_ws, size_t ws_size,
                              hipStream_t stream) {
  const float* x    = (const float*)d_in[0];
  const float* wg   = (const float*)d_in[1];
  const float* bias = (const float*)d_in[2];
  const float* wcfc = (const float*)d_in[3];

  float* y     = (float*)d_out;
  float* probs = y + (size_t)N_TOK * C_DIM;
  __bf16* buf  = (__bf16*)d_out;         // slot buffers packed in y region

  char* ws   = (char*)d_ws;
  int*    cnt  = (int*)(ws + WS_CNT);
  int*    perm = (int*)(ws + WS_PERM);
  __bf16* xb   = (__bf16*)(ws + WS_XB);
  __bf16* Wt   = (__bf16*)(ws + WS_WT);

  hipMemsetAsync(cnt, 0, N_EXP * sizeof(int), stream);

  prep_kernel<<<256 + 512, 256, 0, stream>>>(x, wg, bias, wcfc, xb, probs,
                                             Wt, cnt, perm);
  // 8 experts x 8 n-blocks x up to 32 m-blocks (CAP/128); early-exit on count
  moe_gemm<<<8 * 8 * 32, 512, 0, stream>>>(xb, Wt, cnt, perm, buf);
  combine<<<N_TOK, 256, 0, stream>>>(probs, y);
}